// Round 2
// baseline (886.102 us; speedup 1.0000x reference)
//
#include <hip/hip_runtime.h>
#include <math.h>

// Problem constants (fixed by setup_inputs)
static constexpr int BATCH = 32;
static constexpr int NPRED = 512;   // outputs rows (LAP columns)
static constexpr int NTGT  = 200;   // targets rows (LAP rows)
static constexpr int DIM   = 768;
#define BIGF 1e9f                   // fresh-minv init (matches reference BIG)
#define QNANF __int_as_float(0x7fc00000)  // 'used' sentinel: NaN
// NaN-sentinel invariants (all exact): cur < NaN == false; NaN - delta == NaN;
// fminf(x, NaN) == x (C99); ballot(lval==wmin) excludes NaN lanes.

// ---------------------------------------------------------------------------
// Row squared-norms for BOTH inputs in one launch (round-0 config: best
// measured; identical per-row code and reduction order -> identical bits).
// ---------------------------------------------------------------------------
__global__ __launch_bounds__(64) void norms_kernel(const float* __restrict__ O,
                                                   const float* __restrict__ T,
                                                   float* __restrict__ no_arr,
                                                   float* __restrict__ nt_arr) {
    int row = blockIdx.x;
    const float* src;
    float* dst;
    if (row < BATCH * NPRED) {
        src = O + (size_t)row * DIM;            dst = no_arr + row;
    } else {
        int r2 = row - BATCH * NPRED;
        src = T + (size_t)r2 * DIM;             dst = nt_arr + r2;
    }
    const float4* r = (const float4*)src;
    float s = 0.f;
#pragma unroll
    for (int k = 0; k < 3; ++k) {
        float4 v = r[threadIdx.x + 64 * k];
        s += v.x * v.x + v.y * v.y + v.z * v.z + v.w * v.w;
    }
#pragma unroll
    for (int off = 32; off; off >>= 1) s += __shfl_down(s, off);
    if (threadIdx.x == 0) *dst = s;
}

// ---------------------------------------------------------------------------
// cost[b][m][n] = sqrt(max(nt[m] + no[n] - 2 * dot(T[m], O[n]), 0))
// Round-0 config (best measured): 128(m) x 64(n) tile, 256 threads, 8x4 acc.
// Summation: k-ascending single accumulator chain -> bit-identical cost.
// ---------------------------------------------------------------------------
__global__ __launch_bounds__(256) void cost_kernel(const float* __restrict__ O,
                                                   const float* __restrict__ T,
                                                   const float* __restrict__ no_arr,
                                                   const float* __restrict__ nt_arr,
                                                   float* __restrict__ cost) {
    const int b  = blockIdx.z;
    const int m0 = blockIdx.y * 128;
    const int n0 = blockIdx.x * 64;
    const float* Tb = T + (size_t)b * NTGT * DIM;
    const float* Ob = O + (size_t)b * NPRED * DIM;

    __shared__ __align__(16) float As[32][132];  // [k][m], 132*4B = 33*16B
    __shared__ __align__(16) float Bs[32][68];   // [k][n], 68*4B = 17*16B

    const int tid = threadIdx.x;
    const int tx = tid & 15;   // n/4
    const int ty = tid >> 4;   // m/8

    float acc[8][4] = {};

    for (int k0 = 0; k0 < DIM; k0 += 32) {
        // A: 128 rows x 32 k = 1024 float4, 4/thread (clamped rows)
#pragma unroll
        for (int q = 0; q < 4; ++q) {
            int f = tid + q * 256;
            int r = f >> 3;             // 0..127
            int kk = (f & 7) << 2;
            int gm = m0 + r; if (gm > NTGT - 1) gm = NTGT - 1;
            float4 vA = *(const float4*)(Tb + (size_t)gm * DIM + k0 + kk);
            As[kk + 0][r] = vA.x; As[kk + 1][r] = vA.y;
            As[kk + 2][r] = vA.z; As[kk + 3][r] = vA.w;
        }
        // B: 64 rows x 32 k = 512 float4, 2/thread
#pragma unroll
        for (int q = 0; q < 2; ++q) {
            int f = tid + q * 256;
            int r = f >> 3;             // 0..63
            int kk = (f & 7) << 2;
            float4 vB = *(const float4*)(Ob + (size_t)(n0 + r) * DIM + k0 + kk);
            Bs[kk + 0][r] = vB.x; Bs[kk + 1][r] = vB.y;
            Bs[kk + 2][r] = vB.z; Bs[kk + 3][r] = vB.w;
        }
        __syncthreads();
#pragma unroll
        for (int k = 0; k < 32; ++k) {
            float4 a0 = *(const float4*)&As[k][ty * 8];
            float4 a1 = *(const float4*)&As[k][ty * 8 + 4];
            float4 bv = *(const float4*)&Bs[k][tx * 4];
            float av[8] = {a0.x, a0.y, a0.z, a0.w, a1.x, a1.y, a1.z, a1.w};
#pragma unroll
            for (int i = 0; i < 8; ++i) {
                acc[i][0] += av[i] * bv.x; acc[i][1] += av[i] * bv.y;
                acc[i][2] += av[i] * bv.z; acc[i][3] += av[i] * bv.w;
            }
        }
        __syncthreads();
    }

    {
        float4 nov = *(const float4*)(no_arr + b * NPRED + n0 + (tx << 2));
#pragma unroll
        for (int i = 0; i < 8; ++i) {
            int gm = m0 + ty * 8 + i;
            if (gm < NTGT) {
                float ntv = nt_arr[b * NTGT + gm];
                float4 o;
                o.x = sqrtf(fmaxf(ntv + nov.x - 2.0f * acc[i][0], 0.0f));
                o.y = sqrtf(fmaxf(ntv + nov.y - 2.0f * acc[i][1], 0.0f));
                o.z = sqrtf(fmaxf(ntv + nov.z - 2.0f * acc[i][2], 0.0f));
                o.w = sqrtf(fmaxf(ntv + nov.w - 2.0f * acc[i][3], 0.0f));
                *(float4*)&cost[((size_t)b * NTGT + gm) * NPRED + n0 + (tx << 2)] = o;
            }
        }
    }
}

// ---------------------------------------------------------------------------
// LAP helpers
// ---------------------------------------------------------------------------
__device__ __forceinline__ int rl(int v, int l) {
    return __builtin_amdgcn_readlane(v, l);
}
__device__ __forceinline__ float rlf(float v, int l) {
    return __int_as_float(__builtin_amdgcn_readlane(__float_as_int(v), l));
}
__device__ __forceinline__ int sel8i(const int* a, int s) {
    int r = a[0];
#pragma unroll
    for (int k = 1; k < 8; ++k) r = (s == k) ? a[k] : r;
    return r;
}
__device__ __forceinline__ float sel8f(const float* a, int s) {
    float r = a[0];
#pragma unroll
    for (int k = 1; k < 8; ++k) r = (s == k) ? a[k] : r;
    return r;
}
// Wave-wide min via DPP (VALU-only): lane 63 ends with min of all 64 lanes.
// fminf skips NaN (returns the number) -> used cols drop out naturally.
__device__ __forceinline__ float dpp_min_f32(float x) {
    float t;
    t = __int_as_float(__builtin_amdgcn_update_dpp(__float_as_int(x), __float_as_int(x), 0x111, 0xF, 0xF, false)); x = fminf(x, t);
    t = __int_as_float(__builtin_amdgcn_update_dpp(__float_as_int(x), __float_as_int(x), 0x112, 0xF, 0xF, false)); x = fminf(x, t);
    t = __int_as_float(__builtin_amdgcn_update_dpp(__float_as_int(x), __float_as_int(x), 0x114, 0xF, 0xF, false)); x = fminf(x, t);
    t = __int_as_float(__builtin_amdgcn_update_dpp(__float_as_int(x), __float_as_int(x), 0x118, 0xF, 0xF, false)); x = fminf(x, t);
    t = __int_as_float(__builtin_amdgcn_update_dpp(__float_as_int(x), __float_as_int(x), 0x142, 0xF, 0xF, false)); x = fminf(x, t);
    t = __int_as_float(__builtin_amdgcn_update_dpp(__float_as_int(x), __float_as_int(x), 0x143, 0xF, 0xF, false)); x = fminf(x, t);
    return x;
}
// NaN-safe lane-local argmin tree over 8 values (tie -> lower q; NaN loses).
// node: m = fminf(a,b); pick qa iff m==a (ties -> first; a==NaN -> false).
__device__ __forceinline__ float tree8n(const float* m, int& lq) {
    float v01 = fminf(m[0], m[1]); int q01 = (v01 == m[0]) ? 0 : 1;
    float v23 = fminf(m[2], m[3]); int q23 = (v23 == m[2]) ? 2 : 3;
    float v45 = fminf(m[4], m[5]); int q45 = (v45 == m[4]) ? 4 : 5;
    float v67 = fminf(m[6], m[7]); int q67 = (v67 == m[6]) ? 6 : 7;
    float v03 = fminf(v01, v23);   int q03 = (v03 == v01) ? q01 : q23;
    float v47 = fminf(v45, v67);   int q47 = (v47 == v45) ? q45 : q67;
    float r = fminf(v03, v47);     lq = (r == v03) ? q03 : q47;
    return r;
}

// ---------------------------------------------------------------------------
// Jonker-Volgenant LAP, one wave per batch, zero barriers/LDS reductions in
// the Dijkstra iteration. Bit-exact reference trajectory (verified absmax-0).
// Round 12: 64-slot direct-mapped LDS row cache (128 KiB, free at 1 wave/CU).
// Every scanned row is written to LDS off the critical path; demand loads
// (speculation misses) check the cache first: previously-scanned rows are
// served at LDS latency instead of L2/L3 latency. Tags live in one VGPR
// (lane l = tag of slot l); all cache branches are wave-uniform scalars.
// Numerics/trajectory 100% unchanged. col = lane*8 + q.
// ---------------------------------------------------------------------------
__global__ __launch_bounds__(64) void lap_kernel(const float* __restrict__ cost,
                                                 int* __restrict__ out) {
    const int b = blockIdx.x;
    const int lane = threadIdx.x;
    const float* C = cost + (size_t)b * NTGT * NPRED;
    const float* Cl = C + lane * 8;       // lane's 8-column slice base

    __shared__ float u0[NTGT + 1];        // row duals (stable during a row-step)
    __shared__ __align__(16) float rowcache[64][NPRED];  // 128 KiB row cache

    for (int k = lane; k < NTGT + 1; k += 64) u0[k] = 0.f;

    float v[8], minv[8], up[8];
    int p_arr[8], way_arr[8];
#pragma unroll
    for (int q = 0; q < 8; ++q) {
        v[q] = 0.f; up[q] = 0.f; p_arr[q] = 0; way_arr[q] = 0;
    }
    int tagv = -1;                        // lane l holds row-tag of slot l
    __syncthreads();

    float4 ca = *(const float4*)(Cl);         // prefetch row 0 (row-step i=1)
    float4 cb = *(const float4*)(Cl + 4);
    float4 sa = ca, sb = cb;                  // speculative shadow regs

    for (int i = 1; i <= NTGT; ++i) {
#pragma unroll
        for (int q = 0; q < 8; ++q) minv[q] = BIGF;
        float uI = 0.f;       // u[i] accumulator (virtual col 0), uniform
        float u_i0 = 0.f;     // u of current scan row (row i starts at 0)
        int j0 = 0;
        int j1 = 0;
        int spec_j = 0;       // predicted next winner column (1-based)
        int row_cur = i - 1;  // 0-based row currently held in ca/cb

        for (int it = 0; it <= NPRED; ++it) {
            float c[8];
            c[0] = ca.x; c[1] = ca.y; c[2] = ca.z; c[3] = ca.w;
            c[4] = cb.x; c[5] = cb.y; c[6] = cb.z; c[7] = cb.w;

            // scan row i0: reduced cost, same float order as reference.
            // used cols have minv == NaN: cur < NaN is false -> inert.
            bool used_b[8];
#pragma unroll
            for (int q = 0; q < 8; ++q) {
                used_b[q] = __builtin_isnan(minv[q]);
                float cur = (c[q] - u_i0) - v[q];
                bool imp = cur < minv[q];
                minv[q] = imp ? cur : minv[q];
                way_arr[q] = imp ? j0 : way_arr[q];
            }

            // primary argmin (exact; tie -> lowest column; NaN drops out)
            int lq;
            float lval = tree8n(minv, lq);
            int   psel = sel8i(p_arr, lq);
            float usel = sel8f(up, lq);
            float wmin = rlf(dpp_min_f32(lval), 63);
            unsigned long long mask = __ballot(lval == wmin);
            int w = (int)__builtin_ctzll(mask);
            int qw  = rl(lq, w);
            int i0n = rl(psel, w);              // p[j1]
            float u_n = rlf(usel, w);           // u0[p[j1]] (start-of-row value)
            float delta = wmin;
            j1 = w * 8 + qw + 1;
            bool done = (i0n == 0);
            int nr = i0n - 1;                   // next scan row, 0-based

            if (!done) {
                // demand / hit for the row we must scan next:
                // 1) register shadow (speculation hit), 2) LDS row cache,
                // 3) global demand load. All conditions wave-uniform.
                if (j1 == spec_j) {
                    ca = sa; cb = sb;           // shadow load already complete
                } else {
                    int slot = nr & 63;
                    int tg = rl(tagv, slot);
                    if (tg == nr) {
                        ca = *(const float4*)&rowcache[slot][lane * 8];
                        cb = *(const float4*)&rowcache[slot][lane * 8 + 4];
                    } else {
                        const float* Crow = Cl + (size_t)nr * NPRED;
                        ca = *(const float4*)(Crow);
                        cb = *(const float4*)(Crow + 4);
                    }
                }
                // cheap runner-up speculation for the NEXT iteration, issued
                // before the dual updates (maximum latency cover). Uniform
                // minv shift preserves ordering among old candidates.
                float lv2 = (lane == w) ? QNANF : lval;
                float wm2 = rlf(dpp_min_f32(lv2), 63);
                unsigned long long m2 = __ballot(lv2 == wm2);
                int w2 = (int)__builtin_ctzll(m2);
                int q2 = rl(lq, w2);
                int p2 = rl(psel, w2);
                int sj = w2 * 8 + q2 + 1;
                if (p2 != 0 && sj != spec_j) {
                    const float* Srow = Cl + (size_t)(p2 - 1) * NPRED;
                    sa = *(const float4*)(Srow);
                    sb = *(const float4*)(Srow + 4);
                }
                spec_j = sj;   // if p2==0, a hit implies done (data unused)
            }

            // dual updates (reference order; j1 not yet marked used).
            // x +/- 0.0f is bit-exact; NaN - delta == NaN keeps used cols inert.
            uI += delta;
#pragma unroll
            for (int q = 0; q < 8; ++q) {
                float d0 = used_b[q] ? delta : 0.f;
                v[q]  -= d0;
                up[q] += d0;
                minv[q] -= delta;
            }
            // mark j1 used
            {
                bool lw = (lane == w);
#pragma unroll
                for (int q = 0; q < 8; ++q)
                    minv[q] = (lw && q == qw) ? QNANF : minv[q];
            }

            // cache-write the row just scanned (identical bits on rescans;
            // off the critical chain -- next iteration doesn't depend on it)
            {
                int cslot = row_cur & 63;
                float4 w0; w0.x = c[0]; w0.y = c[1]; w0.z = c[2]; w0.w = c[3];
                float4 w1; w1.x = c[4]; w1.y = c[5]; w1.z = c[6]; w1.w = c[7];
                *(float4*)&rowcache[cslot][lane * 8]     = w0;
                *(float4*)&rowcache[cslot][lane * 8 + 4] = w1;
                tagv = (lane == cslot) ? row_cur : tagv;
            }

            if (done) break;
            row_cur = nr;
            u_i0 = u_n;
            j0 = j1;
        }

        // prefetch next row-step's first scan row (row i, 0-based)
        if (i < NTGT) {
            const float* Crow = Cl + (size_t)i * NPRED;
            ca = *(const float4*)(Crow);
            cb = *(const float4*)(Crow + 4);
        }

        // write back u (pre-augment p): used cols carry u0[p]+deltas in up[]
#pragma unroll
        for (int q = 0; q < 8; ++q) {
            bool usedq = __builtin_isnan(minv[q]);
            if (usedq && p_arr[q] != 0) u0[p_arr[q]] = up[q];
        }
        if (lane == 0) u0[i] = uI;

        // backtrack augmenting path (uniform scalar walk over registers)
        {
            int j = j1;
            for (int s = 0; s <= NPRED; ++s) {
                int ow = (j - 1) >> 3, oq = (j - 1) & 7;
                int wj = rl(sel8i(way_arr, oq), ow);    // way[j]
                int pOfW;
                if (wj == 0) {
                    pOfW = i;                           // p[0] = i (virtual)
                } else {
                    int ow2 = (wj - 1) >> 3, oq2 = (wj - 1) & 7;
                    pOfW = rl(sel8i(p_arr, oq2), ow2);  // old p[way[j]]
                }
#pragma unroll
                for (int q = 0; q < 8; ++q) {
                    bool mine = (lane == ow) && (q == oq);
                    p_arr[q] = mine ? pOfW : p_arr[q];
                }
                if (wj == 0) break;
                j = wj;
            }
        }

        __syncthreads();  // u0 write-back visible before refresh reads
        // refresh up = u0[p[col]] with post-augment p
#pragma unroll
        for (int q = 0; q < 8; ++q) up[q] = u0[p_arr[q]];
    }

    // invert matching: g2p aliased into rowcache (dead after the main loop)
    int* g2p = (int*)&rowcache[0][0];
#pragma unroll
    for (int q = 0; q < 8; ++q) {
        int r = p_arr[q];
        if (r > 0) g2p[r - 1] = lane * 8 + q;
    }
    __syncthreads();

    // sort by pred index via rank counting (values distinct)
    for (int t = lane; t < NTGT; t += 64) {
        int myv = g2p[t];
        int rank = 0;
        for (int l = 0; l < NTGT; ++l) rank += (g2p[l] < myv) ? 1 : 0;
        out[b * 2 * NTGT + rank] = myv;          // index_i: sorted pred indices
        out[b * 2 * NTGT + NTGT + rank] = t;     // index_j: gt index (argsort)
    }
}

extern "C" void kernel_launch(void* const* d_in, const int* in_sizes, int n_in,
                              void* d_out, int out_size, void* d_ws, size_t ws_size,
                              hipStream_t stream) {
    const float* outputs = (const float*)d_in[0];  // [32, 512, 768]
    const float* targets = (const float*)d_in[1];  // [32, 200, 768]
    int* out = (int*)d_out;                        // [32, 2, 200] int32

    float* cost   = (float*)d_ws;                         // [32][200][512]
    float* no_arr = cost + (size_t)BATCH * NTGT * NPRED;  // [32*512]
    float* nt_arr = no_arr + (size_t)BATCH * NPRED;       // [32*200]

    norms_kernel<<<BATCH * (NPRED + NTGT), 64, 0, stream>>>(outputs, targets,
                                                            no_arr, nt_arr);
    cost_kernel<<<dim3(NPRED / 64, (NTGT + 127) / 128, BATCH), 256, 0, stream>>>(
        outputs, targets, no_arr, nt_arr, cost);
    lap_kernel<<<BATCH, 64, 0, stream>>>(cost, out);
}

// Round 3
// 805.024 us; speedup vs baseline: 1.1007x; 1.1007x over previous
//
#include <hip/hip_runtime.h>
#include <math.h>

// Problem constants (fixed by setup_inputs)
static constexpr int BATCH = 32;
static constexpr int NPRED = 512;   // outputs rows (LAP columns)
static constexpr int NTGT  = 200;   // targets rows (LAP rows)
static constexpr int DIM   = 768;
#define BIGF 1e9f                   // fresh-minv init (matches reference BIG)
#define QNANF __int_as_float(0x7fc00000)  // 'used' sentinel: NaN
// NaN-sentinel invariants (all exact): cur < NaN == false; NaN - delta == NaN;
// fminf(x, NaN) == x (C99); take-mask !(x<t)&&!isnan(t) excludes NaN t.

// ---------------------------------------------------------------------------
// Row squared-norms for BOTH inputs in one launch (round-0 config: best
// measured; identical per-row code and reduction order -> identical bits).
// ---------------------------------------------------------------------------
__global__ __launch_bounds__(64) void norms_kernel(const float* __restrict__ O,
                                                   const float* __restrict__ T,
                                                   float* __restrict__ no_arr,
                                                   float* __restrict__ nt_arr) {
    int row = blockIdx.x;
    const float* src;
    float* dst;
    if (row < BATCH * NPRED) {
        src = O + (size_t)row * DIM;            dst = no_arr + row;
    } else {
        int r2 = row - BATCH * NPRED;
        src = T + (size_t)r2 * DIM;             dst = nt_arr + r2;
    }
    const float4* r = (const float4*)src;
    float s = 0.f;
#pragma unroll
    for (int k = 0; k < 3; ++k) {
        float4 v = r[threadIdx.x + 64 * k];
        s += v.x * v.x + v.y * v.y + v.z * v.z + v.w * v.w;
    }
#pragma unroll
    for (int off = 32; off; off >>= 1) s += __shfl_down(s, off);
    if (threadIdx.x == 0) *dst = s;
}

// ---------------------------------------------------------------------------
// cost[b][m][n] = sqrt(max(nt[m] + no[n] - 2 * dot(T[m], O[n]), 0))
// Round-0 config (best measured): 128(m) x 64(n) tile, 256 threads, 8x4 acc.
// Summation: k-ascending single accumulator chain -> bit-identical cost.
// ---------------------------------------------------------------------------
__global__ __launch_bounds__(256) void cost_kernel(const float* __restrict__ O,
                                                   const float* __restrict__ T,
                                                   const float* __restrict__ no_arr,
                                                   const float* __restrict__ nt_arr,
                                                   float* __restrict__ cost) {
    const int b  = blockIdx.z;
    const int m0 = blockIdx.y * 128;
    const int n0 = blockIdx.x * 64;
    const float* Tb = T + (size_t)b * NTGT * DIM;
    const float* Ob = O + (size_t)b * NPRED * DIM;

    __shared__ __align__(16) float As[32][132];  // [k][m], 132*4B = 33*16B
    __shared__ __align__(16) float Bs[32][68];   // [k][n], 68*4B = 17*16B

    const int tid = threadIdx.x;
    const int tx = tid & 15;   // n/4
    const int ty = tid >> 4;   // m/8

    float acc[8][4] = {};

    for (int k0 = 0; k0 < DIM; k0 += 32) {
        // A: 128 rows x 32 k = 1024 float4, 4/thread (clamped rows)
#pragma unroll
        for (int q = 0; q < 4; ++q) {
            int f = tid + q * 256;
            int r = f >> 3;             // 0..127
            int kk = (f & 7) << 2;
            int gm = m0 + r; if (gm > NTGT - 1) gm = NTGT - 1;
            float4 vA = *(const float4*)(Tb + (size_t)gm * DIM + k0 + kk);
            As[kk + 0][r] = vA.x; As[kk + 1][r] = vA.y;
            As[kk + 2][r] = vA.z; As[kk + 3][r] = vA.w;
        }
        // B: 64 rows x 32 k = 512 float4, 2/thread
#pragma unroll
        for (int q = 0; q < 2; ++q) {
            int f = tid + q * 256;
            int r = f >> 3;             // 0..63
            int kk = (f & 7) << 2;
            float4 vB = *(const float4*)(Ob + (size_t)(n0 + r) * DIM + k0 + kk);
            Bs[kk + 0][r] = vB.x; Bs[kk + 1][r] = vB.y;
            Bs[kk + 2][r] = vB.z; Bs[kk + 3][r] = vB.w;
        }
        __syncthreads();
#pragma unroll
        for (int k = 0; k < 32; ++k) {
            float4 a0 = *(const float4*)&As[k][ty * 8];
            float4 a1 = *(const float4*)&As[k][ty * 8 + 4];
            float4 bv = *(const float4*)&Bs[k][tx * 4];
            float av[8] = {a0.x, a0.y, a0.z, a0.w, a1.x, a1.y, a1.z, a1.w};
#pragma unroll
            for (int i = 0; i < 8; ++i) {
                acc[i][0] += av[i] * bv.x; acc[i][1] += av[i] * bv.y;
                acc[i][2] += av[i] * bv.z; acc[i][3] += av[i] * bv.w;
            }
        }
        __syncthreads();
    }

    {
        float4 nov = *(const float4*)(no_arr + b * NPRED + n0 + (tx << 2));
#pragma unroll
        for (int i = 0; i < 8; ++i) {
            int gm = m0 + ty * 8 + i;
            if (gm < NTGT) {
                float ntv = nt_arr[b * NTGT + gm];
                float4 o;
                o.x = sqrtf(fmaxf(ntv + nov.x - 2.0f * acc[i][0], 0.0f));
                o.y = sqrtf(fmaxf(ntv + nov.y - 2.0f * acc[i][1], 0.0f));
                o.z = sqrtf(fmaxf(ntv + nov.z - 2.0f * acc[i][2], 0.0f));
                o.w = sqrtf(fmaxf(ntv + nov.w - 2.0f * acc[i][3], 0.0f));
                *(float4*)&cost[((size_t)b * NTGT + gm) * NPRED + n0 + (tx << 2)] = o;
            }
        }
    }
}

// ---------------------------------------------------------------------------
// LAP helpers
// ---------------------------------------------------------------------------
__device__ __forceinline__ int rl(int v, int l) {
    return __builtin_amdgcn_readlane(v, l);
}
__device__ __forceinline__ float rlf(float v, int l) {
    return __int_as_float(__builtin_amdgcn_readlane(__float_as_int(v), l));
}
__device__ __forceinline__ int sel8i(const int* a, int s) {
    int r = a[0];
#pragma unroll
    for (int k = 1; k < 8; ++k) r = (s == k) ? a[k] : r;
    return r;
}
// Wave-wide min via DPP (VALU-only): lane 63 ends with min of all 64 lanes.
// fminf skips NaN (returns the number) -> used cols drop out naturally.
__device__ __forceinline__ float dpp_min_f32(float x) {
    float t;
    t = __int_as_float(__builtin_amdgcn_update_dpp(__float_as_int(x), __float_as_int(x), 0x111, 0xF, 0xF, false)); x = fminf(x, t);
    t = __int_as_float(__builtin_amdgcn_update_dpp(__float_as_int(x), __float_as_int(x), 0x112, 0xF, 0xF, false)); x = fminf(x, t);
    t = __int_as_float(__builtin_amdgcn_update_dpp(__float_as_int(x), __float_as_int(x), 0x114, 0xF, 0xF, false)); x = fminf(x, t);
    t = __int_as_float(__builtin_amdgcn_update_dpp(__float_as_int(x), __float_as_int(x), 0x118, 0xF, 0xF, false)); x = fminf(x, t);
    t = __int_as_float(__builtin_amdgcn_update_dpp(__float_as_int(x), __float_as_int(x), 0x142, 0xF, 0xF, false)); x = fminf(x, t);
    t = __int_as_float(__builtin_amdgcn_update_dpp(__float_as_int(x), __float_as_int(x), 0x143, 0xF, 0xF, false)); x = fminf(x, t);
    return x;
}

// ---------------------------------------------------------------------------
// Jonker-Volgenant LAP, one wave per batch, zero barriers/LDS in the Dijkstra
// iteration. Bit-exact reference trajectory (structure verified absmax-0).
// Round 13: carried-payload argmin. (1) Lane-local tree carries (col,p,u)
// with each fmin node (replaces tree8n + two serial sel8 chains). (2) Wave
// stage keeps the EXACT fminf DPP spine (bit-identical delta) but carries
// pk=(col<<8)|p and u alongside, selected by take = !(x<t) && !isnan(t):
// take-on-tie prefers t, which always comes from lower lanes => lowest tied
// column wins (identical to the old ballot+ctz semantics); NaN lanes lose.
// One readlane(pk,63) then yields the next row index -> the demand load
// issues ~35 cycles earlier, and delta lands ~25 cycles earlier (gating the
// minv update the next scan depends on). No ballot/ctz/multi-readlane on the
// chain. Numerics/trajectory 100% unchanged. col = lane*8 + q.
// ---------------------------------------------------------------------------
__global__ __launch_bounds__(64) void lap_kernel(const float* __restrict__ cost,
                                                 int* __restrict__ out) {
    const int b = blockIdx.x;
    const int lane = threadIdx.x;
    const int lane8 = lane << 3;
    const float* C = cost + (size_t)b * NTGT * NPRED;
    const float* Cl = C + lane8;          // lane's 8-column slice base

    __shared__ float u0[NTGT + 1];        // row duals (stable during a row-step)
    __shared__ int g2p[NTGT];

    for (int k = lane; k < NTGT + 1; k += 64) u0[k] = 0.f;

    float v[8], minv[8], up[8];
    int p_arr[8], way_arr[8];
#pragma unroll
    for (int q = 0; q < 8; ++q) {
        v[q] = 0.f; up[q] = 0.f; p_arr[q] = 0; way_arr[q] = 0;
    }
    __syncthreads();

    float4 ca = *(const float4*)(Cl);         // prefetch row 0 (row-step i=1)
    float4 cb = *(const float4*)(Cl + 4);
    float4 sa = ca, sb = cb;                  // speculative shadow regs

    for (int i = 1; i <= NTGT; ++i) {
#pragma unroll
        for (int q = 0; q < 8; ++q) minv[q] = BIGF;
        float uI = 0.f;       // u[i] accumulator (virtual col 0), uniform
        float u_i0 = 0.f;     // u of current scan row (row i starts at 0)
        int j0 = 0;
        int j1 = 0;
        int spec_j = 0;       // predicted next winner column (1-based)

        for (int it = 0; it <= NPRED; ++it) {
            float c[8];
            c[0] = ca.x; c[1] = ca.y; c[2] = ca.z; c[3] = ca.w;
            c[4] = cb.x; c[5] = cb.y; c[6] = cb.z; c[7] = cb.w;

            // scan row i0: reduced cost, same float order as reference.
            // used cols have minv == NaN: cur < NaN is false -> inert.
            bool used_b[8];
#pragma unroll
            for (int q = 0; q < 8; ++q) {
                used_b[q] = __builtin_isnan(minv[q]);
                float cur = (c[q] - u_i0) - v[q];
                bool imp = cur < minv[q];
                minv[q] = imp ? cur : minv[q];
                way_arr[q] = imp ? j0 : way_arr[q];
            }

            // lane-local argmin tree with carried (col, p, u) payloads.
            // Node rule (m==a ? A : B): ties -> first (lower q); a==NaN -> B.
            // Value sequence identical to tree8n -> bit-exact.
            float v01 = fminf(minv[0], minv[1]); bool c01 = (v01 == minv[0]);
            int   k01 = c01 ? (lane8 | 0) : (lane8 | 1);
            int   q01 = c01 ? p_arr[0] : p_arr[1];
            float w01 = c01 ? up[0] : up[1];
            float v23 = fminf(minv[2], minv[3]); bool c23 = (v23 == minv[2]);
            int   k23 = c23 ? (lane8 | 2) : (lane8 | 3);
            int   q23 = c23 ? p_arr[2] : p_arr[3];
            float w23 = c23 ? up[2] : up[3];
            float v45 = fminf(minv[4], minv[5]); bool c45 = (v45 == minv[4]);
            int   k45 = c45 ? (lane8 | 4) : (lane8 | 5);
            int   q45 = c45 ? p_arr[4] : p_arr[5];
            float w45 = c45 ? up[4] : up[5];
            float v67 = fminf(minv[6], minv[7]); bool c67 = (v67 == minv[6]);
            int   k67 = c67 ? (lane8 | 6) : (lane8 | 7);
            int   q67 = c67 ? p_arr[6] : p_arr[7];
            float w67 = c67 ? up[6] : up[7];
            float v03 = fminf(v01, v23);         bool c03 = (v03 == v01);
            int   k03 = c03 ? k01 : k23;
            int   q03 = c03 ? q01 : q23;
            float w03 = c03 ? w01 : w23;
            float v47 = fminf(v45, v67);         bool c47 = (v47 == v45);
            int   k47 = c47 ? k45 : k67;
            int   q47 = c47 ? q45 : q67;
            float w47 = c47 ? w45 : w67;
            float lval = fminf(v03, v47);        bool cF  = (lval == v03);
            int   colv = cF ? k03 : k47;          // lane's best column (0-based)
            int   pv   = cF ? q03 : q47;          // p[best col]
            float uv   = cF ? w03 : w47;          // u0[p[best col]]

            // wave argmin: EXACT fminf spine (delta bit-identical), carrying
            // pk=(col<<8)|p and u. take = !(x<t) && !isnan(t): on ties takes
            // t (from lower lanes -> lower col); NaN t never taken; NaN x
            // replaced by any valid t. Out-of-range DPP lanes get old value
            // (bound_ctrl=false) -> self-combine no-op.
            float x = lval;
            int   pk = (colv << 8) | pv;
            float uu = uv;
#define DPP_PAY_STEP(CTRL)                                                     \
            {                                                                  \
                float t  = __int_as_float(__builtin_amdgcn_update_dpp(         \
                    __float_as_int(x), __float_as_int(x), CTRL, 0xF, 0xF, false)); \
                int   tp = __builtin_amdgcn_update_dpp(pk, pk, CTRL, 0xF, 0xF, false); \
                float tu = __int_as_float(__builtin_amdgcn_update_dpp(         \
                    __float_as_int(uu), __float_as_int(uu), CTRL, 0xF, 0xF, false)); \
                bool take = !(x < t) && !__builtin_isnan(t);                   \
                x = fminf(x, t);                                               \
                pk = take ? tp : pk;                                           \
                uu = take ? tu : uu;                                           \
            }
            DPP_PAY_STEP(0x111)
            DPP_PAY_STEP(0x112)
            DPP_PAY_STEP(0x114)
            DPP_PAY_STEP(0x118)
            DPP_PAY_STEP(0x142)
            DPP_PAY_STEP(0x143)
#undef DPP_PAY_STEP

            int pk63 = rl(pk, 63);
            int i0n = pk63 & 0xff;              // p[j1]: next scan row (1-based)
            int col1 = pk63 >> 8;               // winning column (0-based)
            j1 = col1 + 1;
            int w  = col1 >> 3;                 // winner lane
            int qw = col1 & 7;                  // winner q
            float delta = rlf(x, 63);           // == wmin, bit-exact
            float u_n = rlf(uu, 63);            // u0[p[j1]] (start-of-row value)
            bool done = (i0n == 0);

            if (!done) {
                // demand / hit for the row we must scan next
                if (j1 == spec_j) {
                    ca = sa; cb = sb;           // shadow load already complete
                } else {
                    const float* Crow = Cl + (size_t)(i0n - 1) * NPRED;
                    ca = *(const float4*)(Crow);
                    cb = *(const float4*)(Crow + 4);
                }
                // cheap runner-up speculation for the NEXT iteration, issued
                // before the dual updates (maximum latency cover). Uniform
                // minv shift preserves ordering among old candidates.
                float lv2 = (lane == w) ? QNANF : lval;
                float wm2 = rlf(dpp_min_f32(lv2), 63);
                unsigned long long m2 = __ballot(lv2 == wm2);
                int w2 = (int)__builtin_ctzll(m2);
                int col2 = rl(colv, w2);
                int p2 = rl(pv, w2);
                int sj = col2 + 1;
                if (p2 != 0 && sj != spec_j) {
                    const float* Srow = Cl + (size_t)(p2 - 1) * NPRED;
                    sa = *(const float4*)(Srow);
                    sb = *(const float4*)(Srow + 4);
                }
                spec_j = sj;   // if p2==0, a hit implies done (data unused)
            }

            // dual updates (reference order; j1 not yet marked used).
            // x +/- 0.0f is bit-exact; NaN - delta == NaN keeps used cols inert.
            uI += delta;
#pragma unroll
            for (int q = 0; q < 8; ++q) {
                float d0 = used_b[q] ? delta : 0.f;
                v[q]  -= d0;
                up[q] += d0;
                minv[q] -= delta;
            }
            // mark j1 used
            {
                bool lw = (lane == w);
#pragma unroll
                for (int q = 0; q < 8; ++q)
                    minv[q] = (lw && q == qw) ? QNANF : minv[q];
            }

            if (done) break;
            u_i0 = u_n;
            j0 = j1;
        }

        // prefetch next row-step's first scan row (row i, 0-based)
        if (i < NTGT) {
            const float* Crow = Cl + (size_t)i * NPRED;
            ca = *(const float4*)(Crow);
            cb = *(const float4*)(Crow + 4);
        }

        // write back u (pre-augment p): used cols carry u0[p]+deltas in up[]
#pragma unroll
        for (int q = 0; q < 8; ++q) {
            bool usedq = __builtin_isnan(minv[q]);
            if (usedq && p_arr[q] != 0) u0[p_arr[q]] = up[q];
        }
        if (lane == 0) u0[i] = uI;

        // backtrack augmenting path (uniform scalar walk over registers)
        {
            int j = j1;
            for (int s = 0; s <= NPRED; ++s) {
                int ow = (j - 1) >> 3, oq = (j - 1) & 7;
                int wj = rl(sel8i(way_arr, oq), ow);    // way[j]
                int pOfW;
                if (wj == 0) {
                    pOfW = i;                           // p[0] = i (virtual)
                } else {
                    int ow2 = (wj - 1) >> 3, oq2 = (wj - 1) & 7;
                    pOfW = rl(sel8i(p_arr, oq2), ow2);  // old p[way[j]]
                }
#pragma unroll
                for (int q = 0; q < 8; ++q) {
                    bool mine = (lane == ow) && (q == oq);
                    p_arr[q] = mine ? pOfW : p_arr[q];
                }
                if (wj == 0) break;
                j = wj;
            }
        }

        __syncthreads();  // u0 write-back visible before refresh reads
        // refresh up = u0[p[col]] with post-augment p
#pragma unroll
        for (int q = 0; q < 8; ++q) up[q] = u0[p_arr[q]];
    }

    // invert matching: g2p[row] = col (0-based pred index)
#pragma unroll
    for (int q = 0; q < 8; ++q) {
        int r = p_arr[q];
        if (r > 0) g2p[r - 1] = lane8 + q;
    }
    __syncthreads();

    // sort by pred index via rank counting (values distinct)
    for (int t = lane; t < NTGT; t += 64) {
        int myv = g2p[t];
        int rank = 0;
        for (int l = 0; l < NTGT; ++l) rank += (g2p[l] < myv) ? 1 : 0;
        out[b * 2 * NTGT + rank] = myv;          // index_i: sorted pred indices
        out[b * 2 * NTGT + NTGT + rank] = t;     // index_j: gt index (argsort)
    }
}

extern "C" void kernel_launch(void* const* d_in, const int* in_sizes, int n_in,
                              void* d_out, int out_size, void* d_ws, size_t ws_size,
                              hipStream_t stream) {
    const float* outputs = (const float*)d_in[0];  // [32, 512, 768]
    const float* targets = (const float*)d_in[1];  // [32, 200, 768]
    int* out = (int*)d_out;                        // [32, 2, 200] int32

    float* cost   = (float*)d_ws;                         // [32][200][512]
    float* no_arr = cost + (size_t)BATCH * NTGT * NPRED;  // [32*512]
    float* nt_arr = no_arr + (size_t)BATCH * NPRED;       // [32*200]

    norms_kernel<<<BATCH * (NPRED + NTGT), 64, 0, stream>>>(outputs, targets,
                                                            no_arr, nt_arr);
    cost_kernel<<<dim3(NPRED / 64, (NTGT + 127) / 128, BATCH), 256, 0, stream>>>(
        outputs, targets, no_arr, nt_arr, cost);
    lap_kernel<<<BATCH, 64, 0, stream>>>(cost, out);
}

// Round 4
// 763.121 us; speedup vs baseline: 1.1612x; 1.0549x over previous
//
#include <hip/hip_runtime.h>
#include <math.h>

// Problem constants (fixed by setup_inputs)
static constexpr int BATCH = 32;
static constexpr int NPRED = 512;   // outputs rows (LAP columns)
static constexpr int NTGT  = 200;   // targets rows (LAP rows)
static constexpr int DIM   = 768;
#define BIGF 1e9f                   // fresh-minv init (matches reference BIG)
#define QNANF __int_as_float(0x7fc00000)  // 'used' sentinel: NaN
// NaN-sentinel invariants (all exact): cur < NaN == false; NaN - delta == NaN;
// fminf(x, NaN) == x (C99); ballot(lval==wmin) excludes NaN lanes.

// ---------------------------------------------------------------------------
// Row squared-norms for BOTH inputs in one launch (round-0 config, verbatim:
// best measured; identical per-row code and reduction order -> identical bits).
// ---------------------------------------------------------------------------
__global__ __launch_bounds__(64) void norms_kernel(const float* __restrict__ O,
                                                   const float* __restrict__ T,
                                                   float* __restrict__ no_arr,
                                                   float* __restrict__ nt_arr) {
    int row = blockIdx.x;
    const float* src;
    float* dst;
    if (row < BATCH * NPRED) {
        src = O + (size_t)row * DIM;            dst = no_arr + row;
    } else {
        int r2 = row - BATCH * NPRED;
        src = T + (size_t)r2 * DIM;             dst = nt_arr + r2;
    }
    const float4* r = (const float4*)src;
    float s = 0.f;
#pragma unroll
    for (int k = 0; k < 3; ++k) {
        float4 v = r[threadIdx.x + 64 * k];
        s += v.x * v.x + v.y * v.y + v.z * v.z + v.w * v.w;
    }
#pragma unroll
    for (int off = 32; off; off >>= 1) s += __shfl_down(s, off);
    if (threadIdx.x == 0) *dst = s;
}

// ---------------------------------------------------------------------------
// cost[b][m][n] = sqrt(max(nt[m] + no[n] - 2 * dot(T[m], O[n]), 0))
// Round 14: register-prefetch pipeline. Same 128(m) x 64(n) tile, same LDS
// layout ([k][m]/[k][n], strides 132/68), same load addresses, same
// k-ascending single-accumulator FMA chain -> cost bits identical.
// Change: tile t+1's 6 global_load_dwordx4 are ISSUED right after the staging
// barrier and consumed (ds_write) only after tile t's 2048-cycle compute --
// the ~600-900 cyc HBM latency that previously stalled every wave inside the
// staging phase (2-phase stall, only 2 waves/SIMD to cover it) is now fully
// hidden under compute.
// ---------------------------------------------------------------------------
__global__ __launch_bounds__(256) void cost_kernel(const float* __restrict__ O,
                                                   const float* __restrict__ T,
                                                   const float* __restrict__ no_arr,
                                                   const float* __restrict__ nt_arr,
                                                   float* __restrict__ cost) {
    const int b  = blockIdx.z;
    const int m0 = blockIdx.y * 128;
    const int n0 = blockIdx.x * 64;
    const float* Tb = T + (size_t)b * NTGT * DIM;
    const float* Ob = O + (size_t)b * NPRED * DIM;

    __shared__ __align__(16) float As[32][132];  // [k][m], 132*4B = 33*16B
    __shared__ __align__(16) float Bs[32][68];   // [k][n], 68*4B = 17*16B

    const int tid = threadIdx.x;
    const int tx = tid & 15;   // n/4
    const int ty = tid >> 4;   // m/8

    // Per-thread staging coordinates (k0-independent; identical address set
    // and LDS destinations as the round-0 kernel).
    int arow[4], akk[4];
    const float* pA[4];
#pragma unroll
    for (int q = 0; q < 4; ++q) {
        int f = tid + q * 256;
        int r = f >> 3;             // 0..127 (tile row)
        int kk = (f & 7) << 2;
        int gm = m0 + r; if (gm > NTGT - 1) gm = NTGT - 1;
        arow[q] = r; akk[q] = kk;
        pA[q] = Tb + (size_t)gm * DIM + kk;
    }
    int brow[2], bkk[2];
    const float* pB[2];
#pragma unroll
    for (int q = 0; q < 2; ++q) {
        int f = tid + q * 256;
        int r = f >> 3;             // 0..63
        int kk = (f & 7) << 2;
        brow[q] = r; bkk[q] = kk;
        pB[q] = Ob + (size_t)(n0 + r) * DIM + kk;
    }

    float4 rA[4], rB[2];
    // prologue: load tile 0 into registers
#pragma unroll
    for (int q = 0; q < 4; ++q) rA[q] = *(const float4*)(pA[q]);
#pragma unroll
    for (int q = 0; q < 2; ++q) rB[q] = *(const float4*)(pB[q]);

    float acc[8][4] = {};

    for (int t = 0; t < DIM / 32; ++t) {
        // stage tile t: registers -> LDS (waits vmcnt; covered by prior
        // compute for t>0, only the prologue pays full latency once)
#pragma unroll
        for (int q = 0; q < 4; ++q) {
            As[akk[q] + 0][arow[q]] = rA[q].x;
            As[akk[q] + 1][arow[q]] = rA[q].y;
            As[akk[q] + 2][arow[q]] = rA[q].z;
            As[akk[q] + 3][arow[q]] = rA[q].w;
        }
#pragma unroll
        for (int q = 0; q < 2; ++q) {
            Bs[bkk[q] + 0][brow[q]] = rB[q].x;
            Bs[bkk[q] + 1][brow[q]] = rB[q].y;
            Bs[bkk[q] + 2][brow[q]] = rB[q].z;
            Bs[bkk[q] + 3][brow[q]] = rB[q].w;
        }
        __syncthreads();

        // issue tile t+1's global loads NOW; they fly during compute
        if (t + 1 < DIM / 32) {
            int k0n = (t + 1) * 32;
#pragma unroll
            for (int q = 0; q < 4; ++q) rA[q] = *(const float4*)(pA[q] + k0n);
#pragma unroll
            for (int q = 0; q < 2; ++q) rB[q] = *(const float4*)(pB[q] + k0n);
        }

        // compute tile t (identical FMA order -> identical bits)
#pragma unroll
        for (int k = 0; k < 32; ++k) {
            float4 a0 = *(const float4*)&As[k][ty * 8];
            float4 a1 = *(const float4*)&As[k][ty * 8 + 4];
            float4 bv = *(const float4*)&Bs[k][tx * 4];
            float av[8] = {a0.x, a0.y, a0.z, a0.w, a1.x, a1.y, a1.z, a1.w};
#pragma unroll
            for (int i = 0; i < 8; ++i) {
                acc[i][0] += av[i] * bv.x; acc[i][1] += av[i] * bv.y;
                acc[i][2] += av[i] * bv.z; acc[i][3] += av[i] * bv.w;
            }
        }
        __syncthreads();   // readers done before next iter's ds_writes
    }

    {
        float4 nov = *(const float4*)(no_arr + b * NPRED + n0 + (tx << 2));
#pragma unroll
        for (int i = 0; i < 8; ++i) {
            int gm = m0 + ty * 8 + i;
            if (gm < NTGT) {
                float ntv = nt_arr[b * NTGT + gm];
                float4 o;
                o.x = sqrtf(fmaxf(ntv + nov.x - 2.0f * acc[i][0], 0.0f));
                o.y = sqrtf(fmaxf(ntv + nov.y - 2.0f * acc[i][1], 0.0f));
                o.z = sqrtf(fmaxf(ntv + nov.z - 2.0f * acc[i][2], 0.0f));
                o.w = sqrtf(fmaxf(ntv + nov.w - 2.0f * acc[i][3], 0.0f));
                *(float4*)&cost[((size_t)b * NTGT + gm) * NPRED + n0 + (tx << 2)] = o;
            }
        }
    }
}

// ---------------------------------------------------------------------------
// LAP helpers (round-0 verbatim)
// ---------------------------------------------------------------------------
__device__ __forceinline__ int rl(int v, int l) {
    return __builtin_amdgcn_readlane(v, l);
}
__device__ __forceinline__ float rlf(float v, int l) {
    return __int_as_float(__builtin_amdgcn_readlane(__float_as_int(v), l));
}
__device__ __forceinline__ int sel8i(const int* a, int s) {
    int r = a[0];
#pragma unroll
    for (int k = 1; k < 8; ++k) r = (s == k) ? a[k] : r;
    return r;
}
__device__ __forceinline__ float sel8f(const float* a, int s) {
    float r = a[0];
#pragma unroll
    for (int k = 1; k < 8; ++k) r = (s == k) ? a[k] : r;
    return r;
}
// Wave-wide min via DPP (VALU-only): lane 63 ends with min of all 64 lanes.
// fminf skips NaN (returns the number) -> used cols drop out naturally.
__device__ __forceinline__ float dpp_min_f32(float x) {
    float t;
    t = __int_as_float(__builtin_amdgcn_update_dpp(__float_as_int(x), __float_as_int(x), 0x111, 0xF, 0xF, false)); x = fminf(x, t);
    t = __int_as_float(__builtin_amdgcn_update_dpp(__float_as_int(x), __float_as_int(x), 0x112, 0xF, 0xF, false)); x = fminf(x, t);
    t = __int_as_float(__builtin_amdgcn_update_dpp(__float_as_int(x), __float_as_int(x), 0x114, 0xF, 0xF, false)); x = fminf(x, t);
    t = __int_as_float(__builtin_amdgcn_update_dpp(__float_as_int(x), __float_as_int(x), 0x118, 0xF, 0xF, false)); x = fminf(x, t);
    t = __int_as_float(__builtin_amdgcn_update_dpp(__float_as_int(x), __float_as_int(x), 0x142, 0xF, 0xF, false)); x = fminf(x, t);
    t = __int_as_float(__builtin_amdgcn_update_dpp(__float_as_int(x), __float_as_int(x), 0x143, 0xF, 0xF, false)); x = fminf(x, t);
    return x;
}
// NaN-safe lane-local argmin tree over 8 values (tie -> lower q; NaN loses).
// node: m = fminf(a,b); pick qa iff m==a (ties -> first; a==NaN -> false).
__device__ __forceinline__ float tree8n(const float* m, int& lq) {
    float v01 = fminf(m[0], m[1]); int q01 = (v01 == m[0]) ? 0 : 1;
    float v23 = fminf(m[2], m[3]); int q23 = (v23 == m[2]) ? 2 : 3;
    float v45 = fminf(m[4], m[5]); int q45 = (v45 == m[4]) ? 4 : 5;
    float v67 = fminf(m[6], m[7]); int q67 = (v67 == m[6]) ? 6 : 7;
    float v03 = fminf(v01, v23);   int q03 = (v03 == v01) ? q01 : q23;
    float v47 = fminf(v45, v67);   int q47 = (v47 == v45) ? q45 : q67;
    float r = fminf(v03, v47);     lq = (r == v03) ? q03 : q47;
    return r;
}

// ---------------------------------------------------------------------------
// Jonker-Volgenant LAP, one wave per batch, zero barriers/LDS in the Dijkstra
// iteration. Round-0 verbatim (best measured: 579us). Bit-exact reference
// trajectory (structure verified absmax-0 in rounds 4/6/8). R12/R13 lessons:
// this loop is chain-bound at ~1 wave/SIMD; both an LDS row cache (+tag check
// on chain) and a carried-payload argmin (+DPP issue on chain) REGRESSED.
// Do not add instructions to this loop. col = lane*8 + q.
// ---------------------------------------------------------------------------
__global__ __launch_bounds__(64) void lap_kernel(const float* __restrict__ cost,
                                                 int* __restrict__ out) {
    const int b = blockIdx.x;
    const int lane = threadIdx.x;
    const float* C = cost + (size_t)b * NTGT * NPRED;
    const float* Cl = C + lane * 8;       // lane's 8-column slice base

    __shared__ float u0[NTGT + 1];        // row duals (stable during a row-step)
    __shared__ int g2p[NTGT];

    for (int k = lane; k < NTGT + 1; k += 64) u0[k] = 0.f;

    float v[8], minv[8], up[8];
    int p_arr[8], way_arr[8];
#pragma unroll
    for (int q = 0; q < 8; ++q) {
        v[q] = 0.f; up[q] = 0.f; p_arr[q] = 0; way_arr[q] = 0;
    }
    __syncthreads();

    float4 ca = *(const float4*)(Cl);         // prefetch row 0 (row-step i=1)
    float4 cb = *(const float4*)(Cl + 4);
    float4 sa = ca, sb = cb;                  // speculative shadow regs

    for (int i = 1; i <= NTGT; ++i) {
#pragma unroll
        for (int q = 0; q < 8; ++q) minv[q] = BIGF;
        float uI = 0.f;       // u[i] accumulator (virtual col 0), uniform
        float u_i0 = 0.f;     // u of current scan row (row i starts at 0)
        int j0 = 0;
        int j1 = 0;
        int spec_j = 0;       // predicted next winner column (1-based)

        for (int it = 0; it <= NPRED; ++it) {
            float c[8];
            c[0] = ca.x; c[1] = ca.y; c[2] = ca.z; c[3] = ca.w;
            c[4] = cb.x; c[5] = cb.y; c[6] = cb.z; c[7] = cb.w;

            // scan row i0: reduced cost, same float order as reference.
            // used cols have minv == NaN: cur < NaN is false -> inert.
            bool used_b[8];
#pragma unroll
            for (int q = 0; q < 8; ++q) {
                used_b[q] = __builtin_isnan(minv[q]);
                float cur = (c[q] - u_i0) - v[q];
                bool imp = cur < minv[q];
                minv[q] = imp ? cur : minv[q];
                way_arr[q] = imp ? j0 : way_arr[q];
            }

            // primary argmin (exact; tie -> lowest column; NaN drops out)
            int lq;
            float lval = tree8n(minv, lq);
            int   psel = sel8i(p_arr, lq);
            float usel = sel8f(up, lq);
            float wmin = rlf(dpp_min_f32(lval), 63);
            unsigned long long mask = __ballot(lval == wmin);
            int w = (int)__builtin_ctzll(mask);
            int qw  = rl(lq, w);
            int i0n = rl(psel, w);              // p[j1]
            float u_n = rlf(usel, w);           // u0[p[j1]] (start-of-row value)
            float delta = wmin;
            j1 = w * 8 + qw + 1;
            bool done = (i0n == 0);

            if (!done) {
                // demand / hit for the row we must scan next
                if (j1 == spec_j) {
                    ca = sa; cb = sb;           // shadow load already complete
                } else {
                    const float* Crow = Cl + (size_t)(i0n - 1) * NPRED;
                    ca = *(const float4*)(Crow);
                    cb = *(const float4*)(Crow + 4);
                }
                // cheap runner-up speculation for the NEXT iteration, issued
                // before the dual updates (maximum latency cover). Uniform
                // minv shift preserves ordering among old candidates.
                float lv2 = (lane == w) ? QNANF : lval;
                float wm2 = rlf(dpp_min_f32(lv2), 63);
                unsigned long long m2 = __ballot(lv2 == wm2);
                int w2 = (int)__builtin_ctzll(m2);
                int q2 = rl(lq, w2);
                int p2 = rl(psel, w2);
                int sj = w2 * 8 + q2 + 1;
                if (p2 != 0 && sj != spec_j) {
                    const float* Srow = Cl + (size_t)(p2 - 1) * NPRED;
                    sa = *(const float4*)(Srow);
                    sb = *(const float4*)(Srow + 4);
                }
                spec_j = sj;   // if p2==0, a hit implies done (data unused)
            }

            // dual updates (reference order; j1 not yet marked used).
            // x +/- 0.0f is bit-exact; NaN - delta == NaN keeps used cols inert.
            uI += delta;
#pragma unroll
            for (int q = 0; q < 8; ++q) {
                float d0 = used_b[q] ? delta : 0.f;
                v[q]  -= d0;
                up[q] += d0;
                minv[q] -= delta;
            }
            // mark j1 used
            {
                bool lw = (lane == w);
#pragma unroll
                for (int q = 0; q < 8; ++q)
                    minv[q] = (lw && q == qw) ? QNANF : minv[q];
            }

            if (done) break;
            u_i0 = u_n;
            j0 = j1;
        }

        // prefetch next row-step's first scan row (row i, 0-based)
        if (i < NTGT) {
            const float* Crow = Cl + (size_t)i * NPRED;
            ca = *(const float4*)(Crow);
            cb = *(const float4*)(Crow + 4);
        }

        // write back u (pre-augment p): used cols carry u0[p]+deltas in up[]
#pragma unroll
        for (int q = 0; q < 8; ++q) {
            bool usedq = __builtin_isnan(minv[q]);
            if (usedq && p_arr[q] != 0) u0[p_arr[q]] = up[q];
        }
        if (lane == 0) u0[i] = uI;

        // backtrack augmenting path (uniform scalar walk over registers)
        {
            int j = j1;
            for (int s = 0; s <= NPRED; ++s) {
                int ow = (j - 1) >> 3, oq = (j - 1) & 7;
                int wj = rl(sel8i(way_arr, oq), ow);    // way[j]
                int pOfW;
                if (wj == 0) {
                    pOfW = i;                           // p[0] = i (virtual)
                } else {
                    int ow2 = (wj - 1) >> 3, oq2 = (wj - 1) & 7;
                    pOfW = rl(sel8i(p_arr, oq2), ow2);  // old p[way[j]]
                }
#pragma unroll
                for (int q = 0; q < 8; ++q) {
                    bool mine = (lane == ow) && (q == oq);
                    p_arr[q] = mine ? pOfW : p_arr[q];
                }
                if (wj == 0) break;
                j = wj;
            }
        }

        __syncthreads();  // u0 write-back visible before refresh reads
        // refresh up = u0[p[col]] with post-augment p
#pragma unroll
        for (int q = 0; q < 8; ++q) up[q] = u0[p_arr[q]];
    }

    // invert matching: g2p[row] = col (0-based pred index)
#pragma unroll
    for (int q = 0; q < 8; ++q) {
        int r = p_arr[q];
        if (r > 0) g2p[r - 1] = lane * 8 + q;
    }
    __syncthreads();

    // sort by pred index via rank counting (values distinct)
    for (int t = lane; t < NTGT; t += 64) {
        int myv = g2p[t];
        int rank = 0;
        for (int l = 0; l < NTGT; ++l) rank += (g2p[l] < myv) ? 1 : 0;
        out[b * 2 * NTGT + rank] = myv;          // index_i: sorted pred indices
        out[b * 2 * NTGT + NTGT + rank] = t;     // index_j: gt index (argsort)
    }
}

extern "C" void kernel_launch(void* const* d_in, const int* in_sizes, int n_in,
                              void* d_out, int out_size, void* d_ws, size_t ws_size,
                              hipStream_t stream) {
    const float* outputs = (const float*)d_in[0];  // [32, 512, 768]
    const float* targets = (const float*)d_in[1];  // [32, 200, 768]
    int* out = (int*)d_out;                        // [32, 2, 200] int32

    float* cost   = (float*)d_ws;                         // [32][200][512]
    float* no_arr = cost + (size_t)BATCH * NTGT * NPRED;  // [32*512]
    float* nt_arr = no_arr + (size_t)BATCH * NPRED;       // [32*200]

    norms_kernel<<<BATCH * (NPRED + NTGT), 64, 0, stream>>>(outputs, targets,
                                                            no_arr, nt_arr);
    cost_kernel<<<dim3(NPRED / 64, (NTGT + 127) / 128, BATCH), 256, 0, stream>>>(
        outputs, targets, no_arr, nt_arr, cost);
    lap_kernel<<<BATCH, 64, 0, stream>>>(cost, out);
}

// Round 5
// 762.772 us; speedup vs baseline: 1.1617x; 1.0005x over previous
//
#include <hip/hip_runtime.h>
#include <math.h>

// Problem constants (fixed by setup_inputs)
static constexpr int BATCH = 32;
static constexpr int NPRED = 512;   // outputs rows (LAP columns)
static constexpr int NTGT  = 200;   // targets rows (LAP rows)
static constexpr int DIM   = 768;
#define BIGF 1e9f                   // fresh-minv init (matches reference BIG)
#define QNANF __int_as_float(0x7fc00000)  // 'used' sentinel: NaN
// NaN-sentinel invariants (all exact): cur < NaN == false; NaN - delta == NaN;
// fminf(x, NaN) == x (C99); ballot(lval==wmin) excludes NaN lanes.

// ---------------------------------------------------------------------------
// Row squared-norms for BOTH inputs in one launch (round-0 config, verbatim:
// best measured; identical per-row code and reduction order -> identical bits).
// ---------------------------------------------------------------------------
__global__ __launch_bounds__(64) void norms_kernel(const float* __restrict__ O,
                                                   const float* __restrict__ T,
                                                   float* __restrict__ no_arr,
                                                   float* __restrict__ nt_arr) {
    int row = blockIdx.x;
    const float* src;
    float* dst;
    if (row < BATCH * NPRED) {
        src = O + (size_t)row * DIM;            dst = no_arr + row;
    } else {
        int r2 = row - BATCH * NPRED;
        src = T + (size_t)r2 * DIM;             dst = nt_arr + r2;
    }
    const float4* r = (const float4*)src;
    float s = 0.f;
#pragma unroll
    for (int k = 0; k < 3; ++k) {
        float4 v = r[threadIdx.x + 64 * k];
        s += v.x * v.x + v.y * v.y + v.z * v.z + v.w * v.w;
    }
#pragma unroll
    for (int off = 32; off; off >>= 1) s += __shfl_down(s, off);
    if (threadIdx.x == 0) *dst = s;
}

// ---------------------------------------------------------------------------
// cost[b][m][n] = sqrt(max(nt[m] + no[n] - 2 * dot(T[m], O[n]), 0))
// Round 15: XCD-locality swizzle. Flat 512-block grid; inside, blocks are
// remapped so ALL 16 tiles of batch b run on XCD b%8 (hardware round-robin
// wg -> XCD wg%8). The lap_kernel block for batch b lands on XCD b%8 too, so
// the 400 KB matrix of each batch stays resident in ITS OWN XCD's 4 MiB L2
// (4 batches x 400 KB = 1.6 MB per XCD). Previously the 16 tiles were spread
// across all 8 XCDs -> lap demand loads were cross-XCD (~600-900 cyc, counted
// as HBM FETCH). Per-(b,m0,n0) work is IDENTICAL (same addresses, same FMA
// chain) -> cost bits unchanged. Also keeps R14's register-prefetch pipeline.
// Side benefit: T-tile x-siblings now share one XCD L2 (T was re-fetched ~8x).
// ---------------------------------------------------------------------------
__global__ __launch_bounds__(256) void cost_kernel(const float* __restrict__ O,
                                                   const float* __restrict__ T,
                                                   const float* __restrict__ no_arr,
                                                   const float* __restrict__ nt_arr,
                                                   float* __restrict__ cost) {
    // wg -> (b, tile) with b % 8 == wg % 8 (XCD co-location with lap block b)
    const int wg  = blockIdx.x;          // 0..511
    const int xcd = wg & 7;
    const int idx = wg >> 3;             // 0..63
    const int b   = xcd + 8 * (idx >> 4);          // 4 batches per XCD
    const int t0  = idx & 15;                      // 16 tiles per batch
    const int n0  = (t0 & 7) * 64;
    const int m0  = (t0 >> 3) * 128;

    const float* Tb = T + (size_t)b * NTGT * DIM;
    const float* Ob = O + (size_t)b * NPRED * DIM;

    __shared__ __align__(16) float As[32][132];  // [k][m], 132*4B = 33*16B
    __shared__ __align__(16) float Bs[32][68];   // [k][n], 68*4B = 17*16B

    const int tid = threadIdx.x;
    const int tx = tid & 15;   // n/4
    const int ty = tid >> 4;   // m/8

    // Per-thread staging coordinates (k0-independent; identical address set
    // and LDS destinations as the round-0 kernel).
    int arow[4], akk[4];
    const float* pA[4];
#pragma unroll
    for (int q = 0; q < 4; ++q) {
        int f = tid + q * 256;
        int r = f >> 3;             // 0..127 (tile row)
        int kk = (f & 7) << 2;
        int gm = m0 + r; if (gm > NTGT - 1) gm = NTGT - 1;
        arow[q] = r; akk[q] = kk;
        pA[q] = Tb + (size_t)gm * DIM + kk;
    }
    int brow[2], bkk[2];
    const float* pB[2];
#pragma unroll
    for (int q = 0; q < 2; ++q) {
        int f = tid + q * 256;
        int r = f >> 3;             // 0..63
        int kk = (f & 7) << 2;
        brow[q] = r; bkk[q] = kk;
        pB[q] = Ob + (size_t)(n0 + r) * DIM + kk;
    }

    float4 rA[4], rB[2];
    // prologue: load tile 0 into registers
#pragma unroll
    for (int q = 0; q < 4; ++q) rA[q] = *(const float4*)(pA[q]);
#pragma unroll
    for (int q = 0; q < 2; ++q) rB[q] = *(const float4*)(pB[q]);

    float acc[8][4] = {};

    for (int t = 0; t < DIM / 32; ++t) {
        // stage tile t: registers -> LDS (vmcnt wait covered by prior compute)
#pragma unroll
        for (int q = 0; q < 4; ++q) {
            As[akk[q] + 0][arow[q]] = rA[q].x;
            As[akk[q] + 1][arow[q]] = rA[q].y;
            As[akk[q] + 2][arow[q]] = rA[q].z;
            As[akk[q] + 3][arow[q]] = rA[q].w;
        }
#pragma unroll
        for (int q = 0; q < 2; ++q) {
            Bs[bkk[q] + 0][brow[q]] = rB[q].x;
            Bs[bkk[q] + 1][brow[q]] = rB[q].y;
            Bs[bkk[q] + 2][brow[q]] = rB[q].z;
            Bs[bkk[q] + 3][brow[q]] = rB[q].w;
        }
        __syncthreads();

        // issue tile t+1's global loads NOW; they fly during compute
        if (t + 1 < DIM / 32) {
            int k0n = (t + 1) * 32;
#pragma unroll
            for (int q = 0; q < 4; ++q) rA[q] = *(const float4*)(pA[q] + k0n);
#pragma unroll
            for (int q = 0; q < 2; ++q) rB[q] = *(const float4*)(pB[q] + k0n);
        }

        // compute tile t (identical FMA order -> identical bits)
#pragma unroll
        for (int k = 0; k < 32; ++k) {
            float4 a0 = *(const float4*)&As[k][ty * 8];
            float4 a1 = *(const float4*)&As[k][ty * 8 + 4];
            float4 bv = *(const float4*)&Bs[k][tx * 4];
            float av[8] = {a0.x, a0.y, a0.z, a0.w, a1.x, a1.y, a1.z, a1.w};
#pragma unroll
            for (int i = 0; i < 8; ++i) {
                acc[i][0] += av[i] * bv.x; acc[i][1] += av[i] * bv.y;
                acc[i][2] += av[i] * bv.z; acc[i][3] += av[i] * bv.w;
            }
        }
        __syncthreads();   // readers done before next iter's ds_writes
    }

    {
        float4 nov = *(const float4*)(no_arr + b * NPRED + n0 + (tx << 2));
#pragma unroll
        for (int i = 0; i < 8; ++i) {
            int gm = m0 + ty * 8 + i;
            if (gm < NTGT) {
                float ntv = nt_arr[b * NTGT + gm];
                float4 o;
                o.x = sqrtf(fmaxf(ntv + nov.x - 2.0f * acc[i][0], 0.0f));
                o.y = sqrtf(fmaxf(ntv + nov.y - 2.0f * acc[i][1], 0.0f));
                o.z = sqrtf(fmaxf(ntv + nov.z - 2.0f * acc[i][2], 0.0f));
                o.w = sqrtf(fmaxf(ntv + nov.w - 2.0f * acc[i][3], 0.0f));
                *(float4*)&cost[((size_t)b * NTGT + gm) * NPRED + n0 + (tx << 2)] = o;
            }
        }
    }
}

// ---------------------------------------------------------------------------
// LAP helpers (round-0 verbatim)
// ---------------------------------------------------------------------------
__device__ __forceinline__ int rl(int v, int l) {
    return __builtin_amdgcn_readlane(v, l);
}
__device__ __forceinline__ float rlf(float v, int l) {
    return __int_as_float(__builtin_amdgcn_readlane(__float_as_int(v), l));
}
__device__ __forceinline__ int sel8i(const int* a, int s) {
    int r = a[0];
#pragma unroll
    for (int k = 1; k < 8; ++k) r = (s == k) ? a[k] : r;
    return r;
}
__device__ __forceinline__ float sel8f(const float* a, int s) {
    float r = a[0];
#pragma unroll
    for (int k = 1; k < 8; ++k) r = (s == k) ? a[k] : r;
    return r;
}
// Wave-wide min via DPP (VALU-only): lane 63 ends with min of all 64 lanes.
// fminf skips NaN (returns the number) -> used cols drop out naturally.
__device__ __forceinline__ float dpp_min_f32(float x) {
    float t;
    t = __int_as_float(__builtin_amdgcn_update_dpp(__float_as_int(x), __float_as_int(x), 0x111, 0xF, 0xF, false)); x = fminf(x, t);
    t = __int_as_float(__builtin_amdgcn_update_dpp(__float_as_int(x), __float_as_int(x), 0x112, 0xF, 0xF, false)); x = fminf(x, t);
    t = __int_as_float(__builtin_amdgcn_update_dpp(__float_as_int(x), __float_as_int(x), 0x114, 0xF, 0xF, false)); x = fminf(x, t);
    t = __int_as_float(__builtin_amdgcn_update_dpp(__float_as_int(x), __float_as_int(x), 0x118, 0xF, 0xF, false)); x = fminf(x, t);
    t = __int_as_float(__builtin_amdgcn_update_dpp(__float_as_int(x), __float_as_int(x), 0x142, 0xF, 0xF, false)); x = fminf(x, t);
    t = __int_as_float(__builtin_amdgcn_update_dpp(__float_as_int(x), __float_as_int(x), 0x143, 0xF, 0xF, false)); x = fminf(x, t);
    return x;
}
// NaN-safe lane-local argmin tree over 8 values (tie -> lower q; NaN loses).
// node: m = fminf(a,b); pick qa iff m==a (ties -> first; a==NaN -> false).
__device__ __forceinline__ float tree8n(const float* m, int& lq) {
    float v01 = fminf(m[0], m[1]); int q01 = (v01 == m[0]) ? 0 : 1;
    float v23 = fminf(m[2], m[3]); int q23 = (v23 == m[2]) ? 2 : 3;
    float v45 = fminf(m[4], m[5]); int q45 = (v45 == m[4]) ? 4 : 5;
    float v67 = fminf(m[6], m[7]); int q67 = (v67 == m[6]) ? 6 : 7;
    float v03 = fminf(v01, v23);   int q03 = (v03 == v01) ? q01 : q23;
    float v47 = fminf(v45, v67);   int q47 = (v47 == v45) ? q45 : q67;
    float r = fminf(v03, v47);     lq = (r == v03) ? q03 : q47;
    return r;
}

// ---------------------------------------------------------------------------
// Jonker-Volgenant LAP, one wave per batch, zero barriers/LDS in the Dijkstra
// iteration. Round-0 verbatim (best measured: 579us). Bit-exact reference
// trajectory (structure verified absmax-0 in rounds 4/6/8). R12/R13 lessons:
// this loop is chain-bound at ~1 wave/SIMD; both an LDS row cache (+tag check
// on chain) and a carried-payload argmin (+DPP issue on chain) REGRESSED.
// Do not add instructions to this loop. Block b lands on XCD b%8 (round-robin)
// -- cost_kernel co-locates batch b's matrix in that XCD's L2 (R15 swizzle).
// col = lane*8 + q.
// ---------------------------------------------------------------------------
__global__ __launch_bounds__(64) void lap_kernel(const float* __restrict__ cost,
                                                 int* __restrict__ out) {
    const int b = blockIdx.x;
    const int lane = threadIdx.x;
    const float* C = cost + (size_t)b * NTGT * NPRED;
    const float* Cl = C + lane * 8;       // lane's 8-column slice base

    __shared__ float u0[NTGT + 1];        // row duals (stable during a row-step)
    __shared__ int g2p[NTGT];

    for (int k = lane; k < NTGT + 1; k += 64) u0[k] = 0.f;

    float v[8], minv[8], up[8];
    int p_arr[8], way_arr[8];
#pragma unroll
    for (int q = 0; q < 8; ++q) {
        v[q] = 0.f; up[q] = 0.f; p_arr[q] = 0; way_arr[q] = 0;
    }
    __syncthreads();

    float4 ca = *(const float4*)(Cl);         // prefetch row 0 (row-step i=1)
    float4 cb = *(const float4*)(Cl + 4);
    float4 sa = ca, sb = cb;                  // speculative shadow regs

    for (int i = 1; i <= NTGT; ++i) {
#pragma unroll
        for (int q = 0; q < 8; ++q) minv[q] = BIGF;
        float uI = 0.f;       // u[i] accumulator (virtual col 0), uniform
        float u_i0 = 0.f;     // u of current scan row (row i starts at 0)
        int j0 = 0;
        int j1 = 0;
        int spec_j = 0;       // predicted next winner column (1-based)

        for (int it = 0; it <= NPRED; ++it) {
            float c[8];
            c[0] = ca.x; c[1] = ca.y; c[2] = ca.z; c[3] = ca.w;
            c[4] = cb.x; c[5] = cb.y; c[6] = cb.z; c[7] = cb.w;

            // scan row i0: reduced cost, same float order as reference.
            // used cols have minv == NaN: cur < NaN is false -> inert.
            bool used_b[8];
#pragma unroll
            for (int q = 0; q < 8; ++q) {
                used_b[q] = __builtin_isnan(minv[q]);
                float cur = (c[q] - u_i0) - v[q];
                bool imp = cur < minv[q];
                minv[q] = imp ? cur : minv[q];
                way_arr[q] = imp ? j0 : way_arr[q];
            }

            // primary argmin (exact; tie -> lowest column; NaN drops out)
            int lq;
            float lval = tree8n(minv, lq);
            int   psel = sel8i(p_arr, lq);
            float usel = sel8f(up, lq);
            float wmin = rlf(dpp_min_f32(lval), 63);
            unsigned long long mask = __ballot(lval == wmin);
            int w = (int)__builtin_ctzll(mask);
            int qw  = rl(lq, w);
            int i0n = rl(psel, w);              // p[j1]
            float u_n = rlf(usel, w);           // u0[p[j1]] (start-of-row value)
            float delta = wmin;
            j1 = w * 8 + qw + 1;
            bool done = (i0n == 0);

            if (!done) {
                // demand / hit for the row we must scan next
                if (j1 == spec_j) {
                    ca = sa; cb = sb;           // shadow load already complete
                } else {
                    const float* Crow = Cl + (size_t)(i0n - 1) * NPRED;
                    ca = *(const float4*)(Crow);
                    cb = *(const float4*)(Crow + 4);
                }
                // cheap runner-up speculation for the NEXT iteration, issued
                // before the dual updates (maximum latency cover). Uniform
                // minv shift preserves ordering among old candidates.
                float lv2 = (lane == w) ? QNANF : lval;
                float wm2 = rlf(dpp_min_f32(lv2), 63);
                unsigned long long m2 = __ballot(lv2 == wm2);
                int w2 = (int)__builtin_ctzll(m2);
                int q2 = rl(lq, w2);
                int p2 = rl(psel, w2);
                int sj = w2 * 8 + q2 + 1;
                if (p2 != 0 && sj != spec_j) {
                    const float* Srow = Cl + (size_t)(p2 - 1) * NPRED;
                    sa = *(const float4*)(Srow);
                    sb = *(const float4*)(Srow + 4);
                }
                spec_j = sj;   // if p2==0, a hit implies done (data unused)
            }

            // dual updates (reference order; j1 not yet marked used).
            // x +/- 0.0f is bit-exact; NaN - delta == NaN keeps used cols inert.
            uI += delta;
#pragma unroll
            for (int q = 0; q < 8; ++q) {
                float d0 = used_b[q] ? delta : 0.f;
                v[q]  -= d0;
                up[q] += d0;
                minv[q] -= delta;
            }
            // mark j1 used
            {
                bool lw = (lane == w);
#pragma unroll
                for (int q = 0; q < 8; ++q)
                    minv[q] = (lw && q == qw) ? QNANF : minv[q];
            }

            if (done) break;
            u_i0 = u_n;
            j0 = j1;
        }

        // prefetch next row-step's first scan row (row i, 0-based)
        if (i < NTGT) {
            const float* Crow = Cl + (size_t)i * NPRED;
            ca = *(const float4*)(Crow);
            cb = *(const float4*)(Crow + 4);
        }

        // write back u (pre-augment p): used cols carry u0[p]+deltas in up[]
#pragma unroll
        for (int q = 0; q < 8; ++q) {
            bool usedq = __builtin_isnan(minv[q]);
            if (usedq && p_arr[q] != 0) u0[p_arr[q]] = up[q];
        }
        if (lane == 0) u0[i] = uI;

        // backtrack augmenting path (uniform scalar walk over registers)
        {
            int j = j1;
            for (int s = 0; s <= NPRED; ++s) {
                int ow = (j - 1) >> 3, oq = (j - 1) & 7;
                int wj = rl(sel8i(way_arr, oq), ow);    // way[j]
                int pOfW;
                if (wj == 0) {
                    pOfW = i;                           // p[0] = i (virtual)
                } else {
                    int ow2 = (wj - 1) >> 3, oq2 = (wj - 1) & 7;
                    pOfW = rl(sel8i(p_arr, oq2), ow2);  // old p[way[j]]
                }
#pragma unroll
                for (int q = 0; q < 8; ++q) {
                    bool mine = (lane == ow) && (q == oq);
                    p_arr[q] = mine ? pOfW : p_arr[q];
                }
                if (wj == 0) break;
                j = wj;
            }
        }

        __syncthreads();  // u0 write-back visible before refresh reads
        // refresh up = u0[p[col]] with post-augment p
#pragma unroll
        for (int q = 0; q < 8; ++q) up[q] = u0[p_arr[q]];
    }

    // invert matching: g2p[row] = col (0-based pred index)
#pragma unroll
    for (int q = 0; q < 8; ++q) {
        int r = p_arr[q];
        if (r > 0) g2p[r - 1] = lane * 8 + q;
    }
    __syncthreads();

    // sort by pred index via rank counting (values distinct)
    for (int t = lane; t < NTGT; t += 64) {
        int myv = g2p[t];
        int rank = 0;
        for (int l = 0; l < NTGT; ++l) rank += (g2p[l] < myv) ? 1 : 0;
        out[b * 2 * NTGT + rank] = myv;          // index_i: sorted pred indices
        out[b * 2 * NTGT + NTGT + rank] = t;     // index_j: gt index (argsort)
    }
}

extern "C" void kernel_launch(void* const* d_in, const int* in_sizes, int n_in,
                              void* d_out, int out_size, void* d_ws, size_t ws_size,
                              hipStream_t stream) {
    const float* outputs = (const float*)d_in[0];  // [32, 512, 768]
    const float* targets = (const float*)d_in[1];  // [32, 200, 768]
    int* out = (int*)d_out;                        // [32, 2, 200] int32

    float* cost   = (float*)d_ws;                         // [32][200][512]
    float* no_arr = cost + (size_t)BATCH * NTGT * NPRED;  // [32*512]
    float* nt_arr = no_arr + (size_t)BATCH * NPRED;       // [32*200]

    norms_kernel<<<BATCH * (NPRED + NTGT), 64, 0, stream>>>(outputs, targets,
                                                            no_arr, nt_arr);
    // flat grid: wg%8 selects XCD; kernel remaps so batch b's tiles all land
    // on XCD b%8 (co-located with lap block b)
    cost_kernel<<<512, 256, 0, stream>>>(outputs, targets, no_arr, nt_arr, cost);
    lap_kernel<<<BATCH, 64, 0, stream>>>(cost, out);
}